// Round 2
// baseline (6083.109 us; speedup 1.0000x reference)
//
#include <hip/hip_runtime.h>

// Longformer BART encoder layer, MI355X fp32 baseline.
// B=2 S=4096 D=1024 H=16 HD=64 FFN=4096 window(one-sided)=256.

constexpr int CB  = 2;
constexpr int CS  = 4096;
constexpr int CD  = 1024;
constexpr int CH  = 16;
constexpr int CHD = 64;
constexpr int CF  = 4096;
constexpr int CWIN = 256;          // one-sided window
constexpr int CM  = CB * CS;       // 8192 token rows
constexpr float NEGV = -1e9f;

#define TS  64
#define BKG 16

#define FMA16(acc, a, b) do { \
  acc[0][0] += (a).x*(b).x; acc[0][1] += (a).x*(b).y; acc[0][2] += (a).x*(b).z; acc[0][3] += (a).x*(b).w; \
  acc[1][0] += (a).y*(b).x; acc[1][1] += (a).y*(b).y; acc[1][2] += (a).y*(b).z; acc[1][3] += (a).y*(b).w; \
  acc[2][0] += (a).z*(b).x; acc[2][1] += (a).z*(b).y; acc[2][2] += (a).z*(b).z; acc[2][3] += (a).z*(b).w; \
  acc[3][0] += (a).w*(b).x; acc[3][1] += (a).w*(b).y; acc[3][2] += (a).w*(b).z; acc[3][3] += (a).w*(b).w; \
} while (0)

__device__ __forceinline__ float gelu_exact(float x) {
  return 0.5f * x * (1.0f + erff(x * 0.70710678118654752f));
}

// Shared 64x64x16 fp32 tile mainloop. As is [k][m] (transposed), Bs is [k][n].
__device__ __forceinline__ void gemm_mainloop(
    const float* __restrict__ A, const float* __restrict__ Wt,
    int K, int N, int bm, int bn, int tid,
    float (&As)[BKG][TS], float (&Bs)[BKG][TS], float (&acc)[4][4])
{
  const int tx = tid & 15, ty = tid >> 4;
  const int arow = tid >> 2;             // 0..63
  const int acol = (tid & 3) << 2;       // 0,4,8,12
  const int brow = tid >> 4;             // 0..15
  const int bcol = (tid & 15) << 2;      // 0..60
  const float* Ap = A + (size_t)(bm + arow) * K + acol;
  const float* Wp = Wt + (size_t)brow * N + (bn + bcol);
  for (int k0 = 0; k0 < K; k0 += BKG) {
    const float4 av = *(const float4*)Ap;
    const float4 bv = *(const float4*)Wp;
    Ap += BKG;
    Wp += (size_t)BKG * N;
    __syncthreads();                      // previous-iter readers done
    As[acol + 0][arow] = av.x;
    As[acol + 1][arow] = av.y;
    As[acol + 2][arow] = av.z;
    As[acol + 3][arow] = av.w;
    *(float4*)&Bs[brow][bcol] = bv;
    __syncthreads();
#pragma unroll
    for (int kk = 0; kk < BKG; ++kk) {
      const float4 a = *(const float4*)&As[kk][ty << 2];
      const float4 b = *(const float4*)&Bs[kk][tx << 2];
      FMA16(acc, a, b);
    }
  }
}

// ---------------- QKV projection: writes q/k/v as [B,H,S,HD]; q pre-scaled 1/8
__global__ __launch_bounds__(256) void gemm_qkv(
    const float* __restrict__ hs,
    const float* __restrict__ Wq, const float* __restrict__ bq,
    const float* __restrict__ Wk, const float* __restrict__ bk,
    const float* __restrict__ Wv, const float* __restrict__ bv,
    float* __restrict__ q, float* __restrict__ k, float* __restrict__ v)
{
  __shared__ float As[BKG][TS];
  __shared__ float Bs[BKG][TS];
  const int tid = threadIdx.x;
  const int which = blockIdx.z;
  const float* Wt  = (which == 0) ? Wq : (which == 1) ? Wk : Wv;
  const float* bia = (which == 0) ? bq : (which == 1) ? bk : bv;
  float* out       = (which == 0) ? q  : (which == 1) ? k  : v;
  const float mul  = (which == 0) ? 0.125f : 1.0f;   // 1/sqrt(64)

  const int bm = blockIdx.x * TS;
  const int bn = blockIdx.y * TS;
  float acc[4][4] = {};
  gemm_mainloop(hs, Wt, CD, CD, bm, bn, tid, As, Bs, acc);

  const int tx = tid & 15, ty = tid >> 4;
  const int row0 = bm + (ty << 2);
  const int col0 = bn + (tx << 2);
  const int h   = bn >> 6;         // TS==HD==64: whole block is one head
  const int hd0 = col0 & 63;
  const float4 bb = *(const float4*)&bia[col0];
#pragma unroll
  for (int i = 0; i < 4; ++i) {
    const int m = row0 + i;
    const int bidx = m >> 12;      // / CS
    const int s    = m & (CS - 1);
    float4 o;
    o.x = (acc[i][0] + bb.x) * mul;
    o.y = (acc[i][1] + bb.y) * mul;
    o.z = (acc[i][2] + bb.z) * mul;
    o.w = (acc[i][3] + bb.w) * mul;
    *(float4*)&out[(((size_t)bidx * CH + h) * CS + s) * CHD + hd0] = o;
  }
}

// ---------------- generic GEMM: C = A@W + bias (+res | gelu)
// EPI: 0 = bias only, 1 = bias + residual, 2 = bias + gelu
template <int EPI>
__global__ __launch_bounds__(256) void gemm_f32(
    const float* __restrict__ A, const float* __restrict__ Wt,
    const float* __restrict__ bias, const float* __restrict__ res,
    float* __restrict__ C, int M, int N, int K)
{
  __shared__ float As[BKG][TS];
  __shared__ float Bs[BKG][TS];
  const int tid = threadIdx.x;
  const int bm = blockIdx.x * TS;
  const int bn = blockIdx.y * TS;
  float acc[4][4] = {};
  gemm_mainloop(A, Wt, K, N, bm, bn, tid, As, Bs, acc);

  const int tx = tid & 15, ty = tid >> 4;
  const int row0 = bm + (ty << 2);
  const int col0 = bn + (tx << 2);
  const float4 bb = *(const float4*)&bias[col0];
#pragma unroll
  for (int i = 0; i < 4; ++i) {
    float4 o;
    o.x = acc[i][0] + bb.x;
    o.y = acc[i][1] + bb.y;
    o.z = acc[i][2] + bb.z;
    o.w = acc[i][3] + bb.w;
    if (EPI == 1) {
      const float4 r = *(const float4*)&res[(size_t)(row0 + i) * N + col0];
      o.x += r.x; o.y += r.y; o.z += r.z; o.w += r.w;
    }
    if (EPI == 2) {
      o.x = gelu_exact(o.x); o.y = gelu_exact(o.y);
      o.z = gelu_exact(o.z); o.w = gelu_exact(o.w);
    }
    *(float4*)&C[(size_t)(row0 + i) * N + col0] = o;
  }
}

// ---------------- banded (sliding-window) attention, flash-style
// q,k,v: [B,H,S,HD] (q pre-scaled). out: [B,S,D] with col = h*HD+hd.
__global__ __launch_bounds__(256) void attn_win(
    const float* __restrict__ q, const float* __restrict__ k,
    const float* __restrict__ v,
    const float* __restrict__ amask,          // [B,S] additive key mask
    const unsigned char* __restrict__ qmask,  // [B,S] bool is_index_masked
    const float* __restrict__ hmask,          // [H]
    float* __restrict__ out)
{
  const int qt0 = blockIdx.x * 64;
  const int h = blockIdx.y;
  const int b = blockIdx.z;
  const size_t base = ((size_t)b * CH + h) * CS * CHD;
  const float* qp = q + base;
  const float* kp = k + base;
  const float* vp = v + base;

  __shared__ float Qs[CHD][64];        // [d][qrow]
  __shared__ float Ks[CHD][64];        // [d][kcol]
  __shared__ float Vs[64][CHD + 4];    // [kcol][d]
  __shared__ float Ps[64][64 + 4];     // [qrow][kcol]
  __shared__ float Kms[64];

  const int tid = threadIdx.x;
  const int tx = tid & 15, ty = tid >> 4;

  // stage Q transposed
  {
    const int r  = tid >> 2;
    const int c0 = (tid & 3) << 4;
    const float* src = qp + (size_t)(qt0 + r) * CHD + c0;
#pragma unroll
    for (int j = 0; j < 16; j += 4) {
      const float4 t = *(const float4*)(src + j);
      Qs[c0 + j + 0][r] = t.x; Qs[c0 + j + 1][r] = t.y;
      Qs[c0 + j + 2][r] = t.z; Qs[c0 + j + 3][r] = t.w;
    }
  }

  float m_run[4], l_run[4], acc[4][4];
#pragma unroll
  for (int i = 0; i < 4; ++i) {
    m_run[i] = -INFINITY; l_run[i] = 0.f;
#pragma unroll
    for (int j = 0; j < 4; ++j) acc[i][j] = 0.f;
  }

  for (int c = 0; c < 9; ++c) {
    const int k0 = qt0 - 256 + c * 64;
    if (k0 >= CS || k0 + 64 <= 0) continue;   // uniform skip
    __syncthreads();                           // prev readers of Ks/Vs/Ps done
    {
      const int r  = tid >> 2;
      const int c0 = (tid & 3) << 4;
      const int jg = k0 + r;
      if (jg >= 0 && jg < CS) {
        const float* ksrc = kp + (size_t)jg * CHD + c0;
        const float* vsrc = vp + (size_t)jg * CHD + c0;
#pragma unroll
        for (int j = 0; j < 16; j += 4) {
          const float4 t = *(const float4*)(ksrc + j);
          Ks[c0 + j + 0][r] = t.x; Ks[c0 + j + 1][r] = t.y;
          Ks[c0 + j + 2][r] = t.z; Ks[c0 + j + 3][r] = t.w;
          *(float4*)&Vs[r][c0 + j] = *(const float4*)(vsrc + j);
        }
      } else {
        const float4 z = {0.f, 0.f, 0.f, 0.f};
#pragma unroll
        for (int j = 0; j < 16; j += 4) {
          Ks[c0 + j + 0][r] = 0.f; Ks[c0 + j + 1][r] = 0.f;
          Ks[c0 + j + 2][r] = 0.f; Ks[c0 + j + 3][r] = 0.f;
          *(float4*)&Vs[r][c0 + j] = z;
        }
      }
      if (tid < 64) {
        const int jg2 = k0 + tid;
        Kms[tid] = (jg2 >= 0 && jg2 < CS) ? amask[(size_t)b * CS + jg2] : NEGV;
      }
    }
    __syncthreads();

    // scores: s[4q][4k] = Q.K^T (q already scaled)
    float s[4][4] = {};
#pragma unroll
    for (int kk = 0; kk < CHD; ++kk) {
      const float4 a  = *(const float4*)&Qs[kk][ty << 2];
      const float4 bk4 = *(const float4*)&Ks[kk][tx << 2];
      FMA16(s, a, bk4);
    }
    // band + key mask, online softmax update, stash P
#pragma unroll
    for (int i = 0; i < 4; ++i) {
      const int iq = qt0 + (ty << 2) + i;
#pragma unroll
      for (int j = 0; j < 4; ++j) {
        const int jk = k0 + (tx << 2) + j;
        const int d = jk - iq;
        s[i][j] = (d <= CWIN && d >= -CWIN) ? (s[i][j] + Kms[(tx << 2) + j]) : NEGV;
      }
      float mx = fmaxf(fmaxf(s[i][0], s[i][1]), fmaxf(s[i][2], s[i][3]));
      mx = fmaxf(mx, __shfl_xor(mx, 1));
      mx = fmaxf(mx, __shfl_xor(mx, 2));
      mx = fmaxf(mx, __shfl_xor(mx, 4));
      mx = fmaxf(mx, __shfl_xor(mx, 8));
      const float m_new = fmaxf(m_run[i], mx);
      const float sc = expf(m_run[i] - m_new);   // exp(-inf)=0 on first valid
      float rs = 0.f;
#pragma unroll
      for (int j = 0; j < 4; ++j) {
        const float p = (s[i][j] < -5e8f) ? 0.f : expf(s[i][j] - m_new);
        s[i][j] = p;
        rs += p;
      }
      rs += __shfl_xor(rs, 1); rs += __shfl_xor(rs, 2);
      rs += __shfl_xor(rs, 4); rs += __shfl_xor(rs, 8);
      l_run[i] = l_run[i] * sc + rs;
      m_run[i] = m_new;
#pragma unroll
      for (int j = 0; j < 4; ++j) acc[i][j] *= sc;
      float4 pv;
      pv.x = s[i][0]; pv.y = s[i][1]; pv.z = s[i][2]; pv.w = s[i][3];
      *(float4*)&Ps[(ty << 2) + i][tx << 2] = pv;
    }
    __syncthreads();   // P visible to all lanes

    // acc += P @ V
#pragma unroll 8
    for (int kc = 0; kc < 64; ++kc) {
      const float p0 = Ps[(ty << 2) + 0][kc];
      const float p1 = Ps[(ty << 2) + 1][kc];
      const float p2 = Ps[(ty << 2) + 2][kc];
      const float p3 = Ps[(ty << 2) + 3][kc];
      const float4 vv = *(const float4*)&Vs[kc][tx << 2];
      acc[0][0] += p0 * vv.x; acc[0][1] += p0 * vv.y; acc[0][2] += p0 * vv.z; acc[0][3] += p0 * vv.w;
      acc[1][0] += p1 * vv.x; acc[1][1] += p1 * vv.y; acc[1][2] += p1 * vv.z; acc[1][3] += p1 * vv.w;
      acc[2][0] += p2 * vv.x; acc[2][1] += p2 * vv.y; acc[2][2] += p2 * vv.z; acc[2][3] += p2 * vv.w;
      acc[3][0] += p3 * vv.x; acc[3][1] += p3 * vv.y; acc[3][2] += p3 * vv.z; acc[3][3] += p3 * vv.w;
    }
  }

  // finalize: out = (acc / l) * head_mask, zero masked queries
  const float hm = hmask[h];
#pragma unroll
  for (int i = 0; i < 4; ++i) {
    const int iq = qt0 + (ty << 2) + i;
    const bool qm = qmask[(size_t)b * CS + iq] != 0;
    const float scl = (qm ? 0.f : hm) / fmaxf(l_run[i], 1e-30f);
    float4 o;
    o.x = acc[i][0] * scl; o.y = acc[i][1] * scl;
    o.z = acc[i][2] * scl; o.w = acc[i][3] * scl;
    *(float4*)&out[((size_t)b * CS + iq) * CD + h * CHD + (tx << 2)] = o;
  }
}

// ---------------- row LayerNorm over D=1024 (in-place safe)
__global__ __launch_bounds__(256) void ln_f32(
    const float* __restrict__ X, const float* __restrict__ g,
    const float* __restrict__ bt, float* __restrict__ Y)
{
  const int row = blockIdx.x;
  const int tid = threadIdx.x;
  const float4 xv = *(const float4*)(X + (size_t)row * CD + (tid << 2));
  float s  = xv.x + xv.y + xv.z + xv.w;
  float s2 = xv.x * xv.x + xv.y * xv.y + xv.z * xv.z + xv.w * xv.w;
#pragma unroll
  for (int off = 32; off; off >>= 1) {
    s  += __shfl_xor(s, off);
    s2 += __shfl_xor(s2, off);
  }
  __shared__ float red[8];
  const int wv = tid >> 6;
  if ((tid & 63) == 0) { red[wv] = s; red[wv + 4] = s2; }
  __syncthreads();
  s  = red[0] + red[1] + red[2] + red[3];
  s2 = red[4] + red[5] + red[6] + red[7];
  const float mean = s * (1.f / CD);
  const float var  = s2 * (1.f / CD) - mean * mean;
  const float r = rsqrtf(var + 1e-5f);
  const float4 gv = *(const float4*)(g + (tid << 2));
  const float4 bv = *(const float4*)(bt + (tid << 2));
  float4 o;
  o.x = (xv.x - mean) * r * gv.x + bv.x;
  o.y = (xv.y - mean) * r * gv.y + bv.y;
  o.z = (xv.z - mean) * r * gv.z + bv.z;
  o.w = (xv.w - mean) * r * gv.w + bv.w;
  *(float4*)(Y + (size_t)row * CD + (tid << 2)) = o;
}

extern "C" void kernel_launch(void* const* d_in, const int* in_sizes, int n_in,
                              void* d_out, int out_size, void* d_ws, size_t ws_size,
                              hipStream_t stream)
{
  const float* hs    = (const float*)d_in[0];
  const float* amask = (const float*)d_in[1];
  const float* hmask = (const float*)d_in[2];
  const unsigned char* qmask = (const unsigned char*)d_in[3];
  // d_in[4] is_index_global_attn, d_in[5] is_global_attn: all-false/0 config
  const float* Wq = (const float*)d_in[6];
  const float* bq = (const float*)d_in[7];
  const float* Wk = (const float*)d_in[8];
  const float* bk = (const float*)d_in[9];
  const float* Wv = (const float*)d_in[10];
  const float* bv = (const float*)d_in[11];
  const float* Wo = (const float*)d_in[12];
  const float* bo = (const float*)d_in[13];
  const float* ln1g = (const float*)d_in[14];
  const float* ln1b = (const float*)d_in[15];
  const float* W1 = (const float*)d_in[16];
  const float* b1 = (const float*)d_in[17];
  const float* W2 = (const float*)d_in[18];
  const float* b2 = (const float*)d_in[19];
  const float* ln2g = (const float*)d_in[20];
  const float* ln2b = (const float*)d_in[21];

  char* ws = (char*)d_ws;
  const size_t SZ = (size_t)CM * CD * sizeof(float);   // 32 MB
  float* qb   = (float*)(ws + 0 * SZ);
  float* kb   = (float*)(ws + 1 * SZ);
  float* vb   = (float*)(ws + 2 * SZ);
  float* attn = (float*)(ws + 3 * SZ);
  float* tmp  = (float*)(ws + 4 * SZ);
  float* x1   = (float*)(ws + 0 * SZ);   // reuse q after attention
  float* hbuf = (float*)(ws + 1 * SZ);   // 128 MB, reuses k/v/attn/tmp after use
  float* outf = (float*)d_out;

  gemm_qkv<<<dim3(CM / TS, CD / TS, 3), 256, 0, stream>>>(
      hs, Wq, bq, Wk, bk, Wv, bv, qb, kb, vb);
  attn_win<<<dim3(CS / 64, CH, CB), 256, 0, stream>>>(
      qb, kb, vb, amask, qmask, hmask, attn);
  gemm_f32<1><<<dim3(CM / TS, CD / TS), 256, 0, stream>>>(
      attn, Wo, bo, hs, tmp, CM, CD, CD);
  ln_f32<<<CM, 256, 0, stream>>>(tmp, ln1g, ln1b, x1);
  gemm_f32<2><<<dim3(CM / TS, CF / TS), 256, 0, stream>>>(
      x1, W1, b1, nullptr, hbuf, CM, CF, CD);
  gemm_f32<1><<<dim3(CM / TS, CD / TS), 256, 0, stream>>>(
      hbuf, W2, b2, x1, outf, CM, CD, CF);
  ln_f32<<<CM, 256, 0, stream>>>(outf, ln2g, ln2b, outf);
}

// Round 3
// 552.413 us; speedup vs baseline: 11.0119x; 11.0119x over previous
//
#include <hip/hip_runtime.h>

// Longformer BART encoder layer on MI355X — bf16-MFMA pipeline, fp32 accumulate.
// B=2 S=4096 D=1024 H=16 HD=64 FFN=4096 one-sided window=256.

typedef unsigned short ushort_t;
typedef unsigned char uchar_t;
typedef __attribute__((ext_vector_type(8))) short bf16x8;   // 8 bf16 = 4 VGPR
typedef __attribute__((ext_vector_type(4))) float f32x4;

constexpr int CB  = 2;
constexpr int CS  = 4096;
constexpr int CD  = 1024;
constexpr int CH  = 16;
constexpr int CHD = 64;
constexpr int CF  = 4096;
constexpr int CM  = CB * CS;      // 8192
constexpr float NEGV = -1e9f;

__device__ __forceinline__ ushort_t f2bf(float f) {
  unsigned u = __float_as_uint(f);
  unsigned r = u + 0x7FFFu + ((u >> 16) & 1u);   // RNE
  return (ushort_t)(r >> 16);
}
__device__ __forceinline__ float gelu_exact(float x) {
  return 0.5f * x * (1.0f + erff(x * 0.70710678118654752f));
}

// ---- async global->LDS staging of an NROWS x 64-bf16 tile (rows = 128 B).
// LDS dest is linear; source is pre-swizzled so that reads use slot^(row&7).
template <int NROWS>
__device__ __forceinline__ void stage_swz(const ushort_t* __restrict__ src, int stride,
                                          char* lds, int tid) {
  const int lane = tid & 63, w = tid >> 6;
#pragma unroll
  for (int it = 0; it < NROWS / 32; ++it) {
    const int o   = it * 4096 + w * 1024;        // wave-uniform LDS byte base
    const int eo  = o + lane * 16;               // this lane's physical byte
    const int row = eo >> 7;
    const int lslot = ((eo >> 4) & 7) ^ (row & 7);
    const ushort_t* g = src + (size_t)row * stride + lslot * 8;
    __builtin_amdgcn_global_load_lds((const __attribute__((address_space(1))) void*)g,
                                     (__attribute__((address_space(3))) void*)(lds + o),
                                     16, 0, 0);
  }
}

// swizzled ds_read_b128 of one bf16x8 fragment
__device__ __forceinline__ bf16x8 ldsfrag(const char* lds, int row, int slot) {
  return *(const bf16x8*)(lds + row * 128 + (((slot ^ (row & 7)) << 4)));
}

// ---- shared 128x128xK mfma mainloop. A [M][K] bf16, Bt [N][K] bf16.
__device__ __forceinline__ void mfma_mainloop(const ushort_t* __restrict__ A,
                                              const ushort_t* __restrict__ Bt,
                                              int K, int bm, int bn, int tid,
                                              char* As, char* Bs, f32x4 (&acc)[4][4]) {
  const int lane = tid & 63;
  const int wr = tid >> 7, wc = (tid >> 6) & 1;
  for (int k0 = 0; k0 < K; k0 += 64) {
    __syncthreads();
    stage_swz<128>(A + (size_t)bm * K + k0, K, As, tid);
    stage_swz<128>(Bt + (size_t)bn * K + k0, K, Bs, tid);
    __syncthreads();
#pragma unroll
    for (int kk = 0; kk < 2; ++kk) {
      bf16x8 af[4], bfr[4];
#pragma unroll
      for (int m = 0; m < 4; ++m)
        af[m] = ldsfrag(As, wr * 64 + m * 16 + (lane & 15), kk * 4 + (lane >> 4));
#pragma unroll
      for (int n = 0; n < 4; ++n)
        bfr[n] = ldsfrag(Bs, wc * 64 + n * 16 + (lane & 15), kk * 4 + (lane >> 4));
#pragma unroll
      for (int m = 0; m < 4; ++m)
#pragma unroll
        for (int n = 0; n < 4; ++n)
          acc[m][n] = __builtin_amdgcn_mfma_f32_16x16x32_bf16(af[m], bfr[n], acc[m][n], 0, 0, 0);
    }
  }
}

// ---------------- cast fp32 -> bf16 (flat)
__global__ __launch_bounds__(256) void cast_bf16(const float* __restrict__ x,
                                                 ushort_t* __restrict__ y) {
  const size_t i = ((size_t)blockIdx.x * 256 + threadIdx.x) * 4;
  const float4 v = *(const float4*)(x + i);
  ushort4 o;
  o.x = f2bf(v.x); o.y = f2bf(v.y); o.z = f2bf(v.z); o.w = f2bf(v.w);
  *(ushort4*)(y + i) = o;
}

// ---------------- W [K][N] fp32 -> Wt [N][K] bf16
__global__ __launch_bounds__(256) void transpose_cast(const float* __restrict__ W,
                                                      ushort_t* __restrict__ Wt,
                                                      int K, int N) {
  __shared__ float t[64][65];
  const int k0 = blockIdx.x * 64, n0 = blockIdx.y * 64;
  const int ty = threadIdx.x >> 4, tx = threadIdx.x & 15;
#pragma unroll
  for (int rr = 0; rr < 4; ++rr) {
    const int r = rr * 16 + ty;
    const float4 v = *(const float4*)&W[(size_t)(k0 + r) * N + n0 + tx * 4];
    t[r][tx * 4 + 0] = v.x; t[r][tx * 4 + 1] = v.y;
    t[r][tx * 4 + 2] = v.z; t[r][tx * 4 + 3] = v.w;
  }
  __syncthreads();
#pragma unroll
  for (int rr = 0; rr < 4; ++rr) {
    const int rn = rr * 16 + ty;
    ushort4 o;
    o.x = f2bf(t[tx * 4 + 0][rn]); o.y = f2bf(t[tx * 4 + 1][rn]);
    o.z = f2bf(t[tx * 4 + 2][rn]); o.w = f2bf(t[tx * 4 + 3][rn]);
    *(ushort4*)&Wt[(size_t)(n0 + rn) * K + k0 + tx * 4] = o;
  }
}

// ---------------- QKV projection -> q,k [B,H,S,64] bf16 (q pre-scaled), v^T [B,H,64,S] bf16
__global__ __launch_bounds__(256) void gemm_qkv(
    const ushort_t* __restrict__ hsb,
    const ushort_t* __restrict__ WqT, const ushort_t* __restrict__ WkT,
    const ushort_t* __restrict__ WvT,
    const float* __restrict__ bq, const float* __restrict__ bk, const float* __restrict__ bv,
    ushort_t* __restrict__ q, ushort_t* __restrict__ k, ushort_t* __restrict__ vt) {
  __shared__ __align__(16) char As[16384];
  __shared__ __align__(16) char Bs[16384];
  const int tid = threadIdx.x, lane = tid & 63;
  const int wr = tid >> 7, wc = (tid >> 6) & 1;
  const int which = blockIdx.z;
  const ushort_t* Wt = (which == 0) ? WqT : (which == 1) ? WkT : WvT;
  const float* bia   = (which == 0) ? bq  : (which == 1) ? bk  : bv;
  const float mul    = (which == 0) ? 0.125f : 1.0f;
  const int bm = blockIdx.x * 128, bn = blockIdx.y * 128;

  f32x4 acc[4][4] = {};
  mfma_mainloop(hsb, Wt, CD, bm, bn, tid, As, Bs, acc);

#pragma unroll
  for (int m = 0; m < 4; ++m) {
#pragma unroll
    for (int n = 0; n < 4; ++n) {
      const int col = bn + wc * 64 + n * 16 + (lane & 15);
      const int h = col >> 6, hd = col & 63;
      const float bb = bia[col];
      const int r0 = bm + wr * 64 + m * 16 + ((lane >> 4) << 2);
      const int bidx = r0 >> 12;
      const int s0 = r0 & (CS - 1);
      if (which < 2) {
        ushort_t* dst = (which == 0 ? q : k);
#pragma unroll
        for (int i = 0; i < 4; ++i) {
          const float v = (acc[m][n][i] + bb) * mul;
          dst[((((size_t)bidx * CH + h) * CS) + s0 + i) * CHD + hd] = f2bf(v);
        }
      } else {
        ushort4 o;
        o.x = f2bf(acc[m][n][0] + bb); o.y = f2bf(acc[m][n][1] + bb);
        o.z = f2bf(acc[m][n][2] + bb); o.w = f2bf(acc[m][n][3] + bb);
        *(ushort4*)&vt[(((size_t)bidx * CH + h) * CHD + hd) * CS + s0] = o;
      }
    }
  }
}

// ---------------- generic bf16 GEMM with epilogues
// EPI 1: fp32 out = acc + bias + res(fp32).  EPI 2: bf16 out = gelu(acc + bias).
template <int EPI>
__global__ __launch_bounds__(256) void gemm_epi(
    const ushort_t* __restrict__ A, const ushort_t* __restrict__ Bt,
    const float* __restrict__ bias, const float* __restrict__ res,
    float* __restrict__ outF, ushort_t* __restrict__ outB, int N, int K) {
  __shared__ __align__(16) char As[16384];
  __shared__ __align__(16) char Bs[16384];
  const int tid = threadIdx.x, lane = tid & 63;
  const int wr = tid >> 7, wc = (tid >> 6) & 1;
  const int bm = blockIdx.x * 128, bn = blockIdx.y * 128;

  f32x4 acc[4][4] = {};
  mfma_mainloop(A, Bt, K, bm, bn, tid, As, Bs, acc);

#pragma unroll
  for (int m = 0; m < 4; ++m) {
#pragma unroll
    for (int n = 0; n < 4; ++n) {
      const int col = bn + wc * 64 + n * 16 + (lane & 15);
      const float bb = bias[col];
      const int r0 = bm + wr * 64 + m * 16 + ((lane >> 4) << 2);
#pragma unroll
      for (int i = 0; i < 4; ++i) {
        float v = acc[m][n][i] + bb;
        if (EPI == 1) {
          v += res[(size_t)(r0 + i) * N + col];
          outF[(size_t)(r0 + i) * N + col] = v;
        } else {
          outB[(size_t)(r0 + i) * N + col] = f2bf(gelu_exact(v));
        }
      }
    }
  }
}

// ---------------- banded attention, MFMA flash-style.
// q,k: [B,H,S,64] bf16 (q pre-scaled); vt: [B,H,64,S] bf16; out bf16 [B*S, D].
__global__ __launch_bounds__(256) void attn_mfma(
    const ushort_t* __restrict__ qg, const ushort_t* __restrict__ kg,
    const ushort_t* __restrict__ vtg,
    const float* __restrict__ amask, const uchar_t* __restrict__ qmask,
    const float* __restrict__ hmask, ushort_t* __restrict__ outb) {
  __shared__ __align__(16) char Qs[8192];
  __shared__ __align__(16) char Ks[8192];
  __shared__ __align__(16) char Vt[8192];
  __shared__ __align__(16) char Ps[8192];
  const int qt0 = blockIdx.x * 64, h = blockIdx.y, b = blockIdx.z;
  const int tid = threadIdx.x, lane = tid & 63, w = tid >> 6;
  const size_t bh = (size_t)b * CH + h;

  stage_swz<64>(qg + (bh * CS + qt0) * CHD, CHD, Qs, tid);

  f32x4 O[4] = {};
  float m_run[4], l_run[4];
#pragma unroll
  for (int i = 0; i < 4; ++i) { m_run[i] = -INFINITY; l_run[i] = 0.f; }

  for (int c = 0; c < 9; ++c) {
    const int k0 = qt0 - 256 + c * 64;
    if (k0 < 0 || k0 >= CS) continue;          // chunks are fully in or out
    __syncthreads();                            // prev chunk reads done
    stage_swz<64>(kg + (bh * CS + k0) * CHD, CHD, Ks, tid);
    stage_swz<64>(vtg + bh * CHD * CS + k0, CS, Vt, tid);
    __syncthreads();                            // staging (incl. Q first time) visible

    // S = Q @ K^T  (16 q-rows per wave, 64 keys)
    f32x4 s[4] = {};
#pragma unroll
    for (int kk = 0; kk < 2; ++kk) {
      const bf16x8 a = ldsfrag(Qs, w * 16 + (lane & 15), kk * 4 + (lane >> 4));
#pragma unroll
      for (int n = 0; n < 4; ++n) {
        const bf16x8 bb = ldsfrag(Ks, n * 16 + (lane & 15), kk * 4 + (lane >> 4));
        s[n] = __builtin_amdgcn_mfma_f32_16x16x32_bf16(a, bb, s[n], 0, 0, 0);
      }
    }

    // mask + online softmax (rows r = w*16 + (lane>>4)*4 + i, cols k0+n*16+(lane&15))
    float kmv[4]; int keyc[4];
#pragma unroll
    for (int n = 0; n < 4; ++n) {
      keyc[n] = k0 + n * 16 + (lane & 15);
      kmv[n] = amask[(size_t)b * CS + keyc[n]];
    }
    const int qrb = qt0 + w * 16 + ((lane >> 4) << 2);
#pragma unroll
    for (int i = 0; i < 4; ++i) {
      const int qi = qrb + i;
      float mx = -INFINITY;
#pragma unroll
      for (int n = 0; n < 4; ++n) {
        const int d = keyc[n] - qi;
        float x = (d <= 256 && d >= -256) ? (s[n][i] + kmv[n]) : NEGV;
        s[n][i] = x;
        mx = fmaxf(mx, x);
      }
      mx = fmaxf(mx, __shfl_xor(mx, 1));
      mx = fmaxf(mx, __shfl_xor(mx, 2));
      mx = fmaxf(mx, __shfl_xor(mx, 4));
      mx = fmaxf(mx, __shfl_xor(mx, 8));
      const float m_new = fmaxf(m_run[i], mx);
      const float scf = expf(m_run[i] - m_new);
      float rs = 0.f;
#pragma unroll
      for (int n = 0; n < 4; ++n) {
        const float p = expf(s[n][i] - m_new);   // exp(-1e9-x) flushes to 0
        s[n][i] = p;
        rs += p;
      }
      rs += __shfl_xor(rs, 1); rs += __shfl_xor(rs, 2);
      rs += __shfl_xor(rs, 4); rs += __shfl_xor(rs, 8);
      l_run[i] = l_run[i] * scf + rs;
      m_run[i] = m_new;
#pragma unroll
      for (int n = 0; n < 4; ++n) O[n][i] *= scf;
      // stash P (bf16) into swizzled Ps; rows are wave-private
      const int prow = w * 16 + ((lane >> 4) << 2) + i;
#pragma unroll
      for (int n = 0; n < 4; ++n) {
        const int pcol = n * 16 + (lane & 15);
        const int byte = prow * 128 + ((((pcol >> 3) ^ (prow & 7)) << 4)) + ((pcol & 7) << 1);
        *(ushort_t*)(Ps + byte) = f2bf(s[n][i]);
      }
    }
    __syncthreads();   // P visibility across lanes of the wave (conservative)

    // O += P @ V  (A = P rows of this wave, Bt = V^T)
#pragma unroll
    for (int kk = 0; kk < 2; ++kk) {
      const bf16x8 pa = ldsfrag(Ps, w * 16 + (lane & 15), kk * 4 + (lane >> 4));
#pragma unroll
      for (int nd = 0; nd < 4; ++nd) {
        const bf16x8 vv = ldsfrag(Vt, nd * 16 + (lane & 15), kk * 4 + (lane >> 4));
        O[nd] = __builtin_amdgcn_mfma_f32_16x16x32_bf16(pa, vv, O[nd], 0, 0, 0);
      }
    }
  }

  const float hm = hmask[h];
#pragma unroll
  for (int i = 0; i < 4; ++i) {
    const int qi = qt0 + w * 16 + ((lane >> 4) << 2) + i;
    const bool qm = qmask[(size_t)b * CS + qi] != 0;
    const float scl = (qm ? 0.f : hm) / fmaxf(l_run[i], 1e-30f);
#pragma unroll
    for (int nd = 0; nd < 4; ++nd) {
      const int col = h * CHD + nd * 16 + (lane & 15);
      outb[((size_t)b * CS + qi) * CD + col] = f2bf(O[nd][i] * scl);
    }
  }
}

// ---------------- LayerNorm over D=1024; optional bf16 secondary output
__global__ __launch_bounds__(256) void ln_f32(const float* __restrict__ X,
                                              const float* __restrict__ g,
                                              const float* __restrict__ bt,
                                              float* __restrict__ Y,
                                              ushort_t* __restrict__ Yb) {
  const int row = blockIdx.x;
  const int tid = threadIdx.x;
  const float4 xv = *(const float4*)(X + (size_t)row * CD + (tid << 2));
  float s  = xv.x + xv.y + xv.z + xv.w;
  float s2 = xv.x * xv.x + xv.y * xv.y + xv.z * xv.z + xv.w * xv.w;
#pragma unroll
  for (int off = 32; off; off >>= 1) {
    s  += __shfl_xor(s, off);
    s2 += __shfl_xor(s2, off);
  }
  __shared__ float red[8];
  const int wv = tid >> 6;
  if ((tid & 63) == 0) { red[wv] = s; red[wv + 4] = s2; }
  __syncthreads();
  s  = red[0] + red[1] + red[2] + red[3];
  s2 = red[4] + red[5] + red[6] + red[7];
  const float mean = s * (1.f / CD);
  const float var  = s2 * (1.f / CD) - mean * mean;
  const float r = rsqrtf(var + 1e-5f);
  const float4 gv = *(const float4*)(g + (tid << 2));
  const float4 bv = *(const float4*)(bt + (tid << 2));
  float4 o;
  o.x = (xv.x - mean) * r * gv.x + bv.x;
  o.y = (xv.y - mean) * r * gv.y + bv.y;
  o.z = (xv.z - mean) * r * gv.z + bv.z;
  o.w = (xv.w - mean) * r * gv.w + bv.w;
  *(float4*)(Y + (size_t)row * CD + (tid << 2)) = o;
  if (Yb) {
    ushort4 ob;
    ob.x = f2bf(o.x); ob.y = f2bf(o.y); ob.z = f2bf(o.z); ob.w = f2bf(o.w);
    *(ushort4*)(Yb + (size_t)row * CD + (tid << 2)) = ob;
  }
}

extern "C" void kernel_launch(void* const* d_in, const int* in_sizes, int n_in,
                              void* d_out, int out_size, void* d_ws, size_t ws_size,
                              hipStream_t stream) {
  const float* hs    = (const float*)d_in[0];
  const float* amask = (const float*)d_in[1];
  const float* hmask = (const float*)d_in[2];
  const uchar_t* qmask = (const uchar_t*)d_in[3];
  const float* Wq = (const float*)d_in[6];
  const float* bq = (const float*)d_in[7];
  const float* Wk = (const float*)d_in[8];
  const float* bk = (const float*)d_in[9];
  const float* Wv = (const float*)d_in[10];
  const float* bv = (const float*)d_in[11];
  const float* Wo = (const float*)d_in[12];
  const float* bo = (const float*)d_in[13];
  const float* ln1g = (const float*)d_in[14];
  const float* ln1b = (const float*)d_in[15];
  const float* W1 = (const float*)d_in[16];
  const float* b1 = (const float*)d_in[17];
  const float* W2 = (const float*)d_in[18];
  const float* b2 = (const float*)d_in[19];
  const float* ln2g = (const float*)d_in[20];
  const float* ln2b = (const float*)d_in[21];

  char* ws = (char*)d_ws;
  const size_t MB = 1024 * 1024;
  // activations / weights (bf16 unless noted)
  ushort_t* hsb  = (ushort_t*)(ws);                       // 16 MB [0,16)
  ushort_t* WqT  = (ushort_t*)(ws + 16 * MB);             //  2 MB
  ushort_t* WkT  = (ushort_t*)(ws + 18 * MB);
  ushort_t* WvT  = (ushort_t*)(ws + 20 * MB);
  ushort_t* WoT  = (ushort_t*)(ws + 22 * MB);
  ushort_t* W1T  = (ushort_t*)(ws + 24 * MB);             //  8 MB
  ushort_t* W2T  = (ushort_t*)(ws + 32 * MB);             //  8 MB -> ends 40
  ushort_t* qb   = (ushort_t*)(ws + 40 * MB);             // 16 MB
  ushort_t* kb   = (ushort_t*)(ws + 56 * MB);             // 16 MB
  ushort_t* vtb  = (ushort_t*)(ws + 72 * MB);             // 16 MB
  ushort_t* attb = (ushort_t*)(ws + 88 * MB);             // 16 MB
  float*    tmp  = (float*)(ws + 104 * MB);               // 32 MB -> ends 136
  // reuse after attention:
  float*    x1   = (float*)(ws + 40 * MB);                // 32 MB over qb+kb (dead)
  ushort_t* x1b  = (ushort_t*)(ws + 72 * MB);             // 16 MB over vtb (dead after attn)
  ushort_t* hb   = (ushort_t*)(ws + 136 * MB);            // 64 MB -> ends 200
  float*    outf = (float*)d_out;

  // 0) casts + weight transposes
  cast_bf16<<<(CM * CD) / 1024, 256, 0, stream>>>(hs, hsb);
  transpose_cast<<<dim3(CD / 64, CD / 64), 256, 0, stream>>>(Wq, WqT, CD, CD);
  transpose_cast<<<dim3(CD / 64, CD / 64), 256, 0, stream>>>(Wk, WkT, CD, CD);
  transpose_cast<<<dim3(CD / 64, CD / 64), 256, 0, stream>>>(Wv, WvT, CD, CD);
  transpose_cast<<<dim3(CD / 64, CD / 64), 256, 0, stream>>>(Wo, WoT, CD, CD);
  transpose_cast<<<dim3(CD / 64, CF / 64), 256, 0, stream>>>(W1, W1T, CD, CF);
  transpose_cast<<<dim3(CF / 64, CD / 64), 256, 0, stream>>>(W2, W2T, CF, CD);

  // 1) QKV projection
  gemm_qkv<<<dim3(CM / 128, CD / 128, 3), 256, 0, stream>>>(
      hsb, WqT, WkT, WvT, bq, bk, bv, qb, kb, vtb);

  // 2) sliding-window attention
  attn_mfma<<<dim3(CS / 64, CH, CB), 256, 0, stream>>>(
      qb, kb, vtb, amask, qmask, hmask, attb);

  // 3) Wo projection + residual -> tmp (fp32)
  gemm_epi<1><<<dim3(CM / 128, CD / 128), 256, 0, stream>>>(
      attb, WoT, bo, hs, tmp, nullptr, CD, CD);

  // 4) LN1 -> x1 fp32 + x1b bf16
  ln_f32<<<CM, 256, 0, stream>>>(tmp, ln1g, ln1b, x1, x1b);

  // 5) FFN1 + GELU -> hb bf16
  gemm_epi<2><<<dim3(CM / 128, CF / 128), 256, 0, stream>>>(
      x1b, W1T, b1, nullptr, nullptr, hb, CF, CD);

  // 6) FFN2 + residual -> d_out fp32
  gemm_epi<1><<<dim3(CM / 128, CD / 128), 256, 0, stream>>>(
      hb, W2T, b2, x1, outf, nullptr, CD, CF);

  // 7) LN2 in place
  ln_f32<<<CM, 256, 0, stream>>>(outf, ln2g, ln2b, outf, nullptr);
}